// Round 1
// baseline (232.803 us; speedup 1.0000x reference)
//
#include <hip/hip_runtime.h>
#include <hip/hip_bf16.h>
#include <stdint.h>
#include <stddef.h>

// BiAttentionLayer: B=8, Tc=4096, Tq=1024, D=256, fp32 in/out.
// Math: s_c (w1) cancels in softmax/U/b. exp without running max is safe
// (|S+s_q| <= ~15). b[i] = exp(m)/l.
// Round-2: 16-i waves (16x16x32 MFMA) to cut accumulator regs, 4-wave blocks
// share staged q-tile, mm2 B direct from L2 (swizzled layout).
// Round-3 (this round): 2-phase pipeline in k_main —
//   * qa tile staged via global_load_lds (width=16) into a double buffer,
//     issued at TOP of iteration -> overlaps mm1+softmax+mm2; ONE barrier/iter
//     (was: serial load->ds_write->drain->barrier->compute->barrier).
//   * s_q hoisted to LDS once in the prologue (4 KiB) instead of per-iter.

#define NB 8
#define TC 4096
#define TQ 1024
#define DD 256
#define JT 32
#define NJT (TQ / JT)

typedef __attribute__((ext_vector_type(4)))  float  f32x4v;
typedef __attribute__((ext_vector_type(8)))  __bf16 bf16x8v;
typedef __attribute__((ext_vector_type(4)))  __bf16 bf16x4v;

// workspace layout (bytes)
#define QA_OFF   0                              // bf16 frag-order for mm1 A: [b][it][jm][c][L][8]  (4 MiB)
#define QX_OFF   (QA_OFF + NB*NJT*16*1024)      // bf16 frag-order for mm2 B: [b][it][mt][L][8]     (4 MiB)
#define SQ_OFF   (QX_OFF + NB*NJT*16*1024)      // f32 [NB][TQ]
#define BV_OFF   (SQ_OFF + NB*TQ*4)             // f32 [NB][TC]
#define HV_OFF   (BV_OFF + NB*TC*4)             // f32 [NB][DD]

__device__ __forceinline__ void async_cp16(const void* g, void* l) {
  __builtin_amdgcn_global_load_lds(
      (const __attribute__((address_space(1))) void*)g,
      (__attribute__((address_space(3))) void*)l, 16, 0, 0);
}

// ---------------- kernel 0: question preprocessing ----------------
// One block per (b, jtile): stage q-tile bf16 in LDS, emit both fragment
// layouts + s_q.
__global__ __launch_bounds__(256) void k_qprep(const float* __restrict__ question,
                                               const float* __restrict__ w,
                                               char* __restrict__ ws) {
  uint4* qa = (uint4*)(ws + QA_OFF);
  uint4* qx = (uint4*)(ws + QX_OFF);
  float* sq = (float*)(ws + SQ_OFF);
  __shared__ __align__(16) __bf16 T[32][264];   // 528 B row stride (16-aligned)

  int bx = blockIdx.x;
  int b = bx >> 5, it = bx & 31;
  int t = threadIdx.x;
  int j = t >> 3;         // 0..31
  int seg = t & 7;        // d segment of 32

  const float* qrow = question + ((size_t)(b * TQ + it * JT + j)) * DD + seg * 32;
  const float* w2 = w + DD;

  float part = 0.f;
#pragma unroll
  for (int k = 0; k < 8; ++k) {
    float4 v  = *(const float4*)(qrow + 4 * k);
    float4 wv = *(const float4*)(w2 + seg * 32 + 4 * k);
    part += v.x * wv.x + v.y * wv.y + v.z * wv.z + v.w * wv.w;
    bf16x4v pk = {(__bf16)v.x, (__bf16)v.y, (__bf16)v.z, (__bf16)v.w};
    *(bf16x4v*)&T[j][seg * 32 + 4 * k] = pk;
  }
  part += __shfl_xor(part, 1);
  part += __shfl_xor(part, 2);
  part += __shfl_xor(part, 4);
  if (seg == 0) sq[b * TQ + it * JT + j] = part;
  __syncthreads();

  // qa chunks: ch = (jm*8+c)*64 + L ; element T[16*jm + (L&15)][32*c + 8*(L>>4) + o]
#pragma unroll
  for (int p = 0; p < 4; ++p) {
    int ch = t + 256 * p;
    int L = ch & 63, cc = ch >> 6;
    int jm = cc >> 3, c = cc & 7;
    int nh = L & 15, qh = L >> 4;
    uint4 v = *(const uint4*)&T[16 * jm + nh][32 * c + 8 * qh];
    qa[(size_t)(b * NJT + it) * 1024 + ch] = v;
  }
  // qx chunks: ch = mt*64 + L ; element T[8*(L>>4) + o][16*mt + (L&15)]
#pragma unroll
  for (int p = 0; p < 4; ++p) {
    int ch = t + 256 * p;
    int L = ch & 63, mt = ch >> 6;
    int nh = L & 15, qh = L >> 4;
    __bf16 e[8];
#pragma unroll
    for (int o = 0; o < 8; ++o) e[o] = T[8 * qh + o][16 * mt + nh];
    qx[(size_t)(b * NJT + it) * 1024 + ch] = *(const uint4*)e;
  }
}

// ---------------- kernel 1: fused scores+softmax+U + G chunks 0/1/2 ----------------
// 512 blocks x 256 thr (4 waves). Block owns 64 i; wave w owns 16 i.
// mm1: S^T[32j][16i] = q . cw3^T  (A = staged qa frags, B = cw3 regs)
// mm2: U[16i][256d] += P . q      (A = P via tiny per-wave LDS, B = qx from L2)
// 2-phase pipeline: stage(next qa tile) via global_load_lds at top, compute
// current, single __syncthreads (vmcnt(0)+lgkmcnt(0) drain) at bottom.
__global__ __launch_bounds__(256, 2) void k_main(const float* __restrict__ context,
                                                 const float* __restrict__ w,
                                                 const char* __restrict__ ws,
                                                 float* __restrict__ bv_out,
                                                 float* __restrict__ out) {
  const uint4*  qa = (const uint4*)(ws + QA_OFF);
  const __bf16* qx = (const __bf16*)(ws + QX_OFF);
  const float*  sq = (const float*)(ws + SQ_OFF);

  __shared__ __align__(16) __bf16 qa_lds[2][8192];   // 2 x 16 KiB double buffer
  __shared__ __align__(16) __bf16 pa_lds[4][16][40]; // per-wave P buffer (80 B rows)
  __shared__ __align__(16) float  sq_all[TQ];        // all s_q for this batch (4 KiB)

  int bx = blockIdx.x;
  int b = bx & 7;                 // XCD-affine batch mapping
  int ig = bx >> 3;               // 0..63
  int t = threadIdx.x;
  int wv = t >> 6;
  int lane = t & 63;
  int nh = lane & 15;             // col index (i for mm1 out, d for mm2 out)
  int qh = lane >> 4;             // quad
  int i0w = ig * 64 + wv * 16;    // wave's first i

  const uint4* qa_b = qa + (size_t)b * NJT * 1024;
  const __bf16* qx_b = qx + (size_t)b * NJT * 8192;
  const float* sqb = sq + b * TQ;

  // cw3 B-frags: B[k=d][n=i] = context[i0w+nh][d]*w3[d], d = 32c + 8qh + o
  bf16x8v cw3f[8];
  {
    const float* crow = context + ((size_t)(b * TC + i0w + nh)) * DD;
    const float* w3 = w + 2 * DD;
#pragma unroll
    for (int c = 0; c < 8; ++c) {
      int d0 = 32 * c + 8 * qh;
      float4 f0 = *(const float4*)(crow + d0);
      float4 f1 = *(const float4*)(crow + d0 + 4);
      float4 g0 = *(const float4*)(w3 + d0);
      float4 g1 = *(const float4*)(w3 + d0 + 4);
      bf16x8v fr;
      fr[0] = (__bf16)(f0.x * g0.x); fr[1] = (__bf16)(f0.y * g0.y);
      fr[2] = (__bf16)(f0.z * g0.z); fr[3] = (__bf16)(f0.w * g0.w);
      fr[4] = (__bf16)(f1.x * g1.x); fr[5] = (__bf16)(f1.y * g1.y);
      fr[6] = (__bf16)(f1.z * g1.z); fr[7] = (__bf16)(f1.w * g1.w);
      cw3f[c] = fr;
    }
  }

  // prologue: stage s_q for the whole batch (4 KiB) + qa tile 0 into buf 0
  {
    ((float4*)sq_all)[t] = ((const float4*)sqb)[t];
    const uint4* src = qa_b;  // tile 0
#pragma unroll
    for (int p = 0; p < 4; ++p) {
      int cb = wv * 64 + p * 256;                 // wave-uniform chunk base
      async_cp16(src + cb + lane, &qa_lds[0][(size_t)cb * 8]);
    }
  }

  f32x4v U[16];
#pragma unroll
  for (int mt = 0; mt < 16; ++mt) U[mt] = (f32x4v){0.f, 0.f, 0.f, 0.f};
  float m_run = -1e30f, l_run = 0.f;

  __syncthreads();   // drains vmcnt(0): tile 0 staged, sq_all visible

  for (int itq = 0; itq < NJT; ++itq) {
    int cur = itq & 1;

    // stage NEXT qa tile into the spare buffer; stays in flight across
    // mm1 (lgkm-only waits) and is drained by the barrier at loop bottom.
    if (itq + 1 < NJT) {
      const uint4* src = qa_b + (size_t)(itq + 1) * 1024;
#pragma unroll
      for (int p = 0; p < 4; ++p) {
        int cb = wv * 64 + p * 256;
        async_cp16(src + cb + lane, &qa_lds[cur ^ 1][(size_t)cb * 8]);
      }
    }

    // mm1: S^T[32j][16i], K=256 in 8 chunks of 32
    f32x4v S0 = {0.f, 0.f, 0.f, 0.f}, S1 = {0.f, 0.f, 0.f, 0.f};
#pragma unroll
    for (int c = 0; c < 8; ++c) {
      bf16x8v a0 = *(const bf16x8v*)&qa_lds[cur][((0 * 8 + c) * 64 + lane) * 8];
      bf16x8v a1 = *(const bf16x8v*)&qa_lds[cur][((1 * 8 + c) * 64 + lane) * 8];
      S0 = __builtin_amdgcn_mfma_f32_16x16x32_bf16(a0, cw3f[c], S0, 0, 0, 0);
      S1 = __builtin_amdgcn_mfma_f32_16x16x32_bf16(a1, cw3f[c], S1, 0, 0, 0);
    }

    // P = exp(S + s_q): lane holds (i=nh, j = 16jm + 4qh + r)
    float4 sq0 = *(const float4*)&sq_all[itq * JT + 4 * qh];
    float4 sq1 = *(const float4*)&sq_all[itq * JT + 16 + 4 * qh];
    float e0 = __expf(S0[0] + sq0.x), e1 = __expf(S0[1] + sq0.y);
    float e2 = __expf(S0[2] + sq0.z), e3 = __expf(S0[3] + sq0.w);
    float f0 = __expf(S1[0] + sq1.x), f1 = __expf(S1[1] + sq1.y);
    float f2 = __expf(S1[2] + sq1.z), f3 = __expf(S1[3] + sq1.w);
    float v0 = fmaxf(fmaxf(S0[0] + sq0.x, S0[1] + sq0.y), fmaxf(S0[2] + sq0.z, S0[3] + sq0.w));
    float v1 = fmaxf(fmaxf(S1[0] + sq1.x, S1[1] + sq1.y), fmaxf(S1[2] + sq1.z, S1[3] + sq1.w));
    m_run = fmaxf(m_run, fmaxf(v0, v1));
    l_run += ((e0 + e1) + (e2 + e3)) + ((f0 + f1) + (f2 + f3));

    // write P to per-wave LDS in A-operand order: pa[i=nh][j]
    bf16x4v pk0 = {(__bf16)e0, (__bf16)e1, (__bf16)e2, (__bf16)e3};
    bf16x4v pk1 = {(__bf16)f0, (__bf16)f1, (__bf16)f2, (__bf16)f3};
    *(bf16x4v*)&pa_lds[wv][nh][4 * qh]      = pk0;
    *(bf16x4v*)&pa_lds[wv][nh][16 + 4 * qh] = pk1;

    // mm2 A-frag: A[m=i=nh][k=j=8qh+o] -> one b128 per lane
    bf16x8v af = *(const bf16x8v*)&pa_lds[wv][nh][8 * qh];

    // mm2: U[16i][16d] per mt, K=32 (full j-tile), B from L2 (coalesced)
    const __bf16* qxt = qx_b + (size_t)itq * 8192 + lane * 8;
#pragma unroll
    for (int mt = 0; mt < 16; ++mt) {
      bf16x8v bq = *(const bf16x8v*)(qxt + mt * 512);
      U[mt] = __builtin_amdgcn_mfma_f32_16x16x32_bf16(af, bq, U[mt], 0, 0, 0);
    }

    // single barrier per iteration: full vmcnt/lgkmcnt drain guarantees
    // (a) next tile fully staged, (b) all reads of the spare buffer done
    // before anyone overwrites it next iteration.
    __syncthreads();
  }

  // reduce l, m across quads (lanes with same nh)
  float lo = l_run + __shfl_xor(l_run, 16);
  lo += __shfl_xor(lo, 32);
  float mo = fmaxf(m_run, __shfl_xor(m_run, 16));
  mo = fmaxf(mo, __shfl_xor(mo, 32));
  float rinv = 1.0f / lo;                 // valid for i = i0w + nh
  if ((t & 63) < 16) bv_out[b * TC + i0w + nh] = __expf(mo) * rinv;

  // epilogue: U rows are i = 4qh + r, cols d = 16mt + nh
  float rv[4];
#pragma unroll
  for (int r = 0; r < 4; ++r) rv[r] = __shfl(rinv, 4 * qh + r);

#pragma unroll
  for (int r = 0; r < 4; ++r) {
    int ig_row = i0w + 4 * qh + r;
    const float* crow = context + ((size_t)(b * TC + ig_row)) * DD;
    float* orow = out + ((size_t)(b * TC + ig_row)) * (4 * DD);
#pragma unroll
    for (int mt = 0; mt < 16; ++mt) {
      int d = 16 * mt + nh;
      float c = crow[d];
      float u = U[mt][r] * rv[r];
      orow[d] = c;
      orow[DD + d] = u;
      orow[2 * DD + d] = c * u;
    }
  }
}

// ---------------- kernel 2: h[b][d] = sum_i b[i] * context[b][i][d] ----------------
__global__ __launch_bounds__(256) void k_hred(const float* __restrict__ context,
                                              const char* __restrict__ ws,
                                              float* __restrict__ hv) {
  const float* bv = (const float*)(ws + BV_OFF);
  __shared__ float bsh[128];
  int bx = blockIdx.x;
  int b = bx >> 5, ch = bx & 31;
  int i0 = ch * 128;
  int t = threadIdx.x;
  if (t < 128) bsh[t] = bv[b * TC + i0 + t];
  __syncthreads();
  float acc = 0.f;
  const float* cp = context + ((size_t)(b * TC + i0)) * DD + t;
#pragma unroll 4
  for (int r = 0; r < 128; ++r) acc += bsh[r] * cp[(size_t)r * DD];
  atomicAdd(&hv[b * DD + t], acc);
}

// ---------------- kernel 3: G chunk 3 = context * H ----------------
__global__ __launch_bounds__(256) void k_final(const float* __restrict__ context,
                                               const char* __restrict__ ws,
                                               float* __restrict__ out) {
  const float* hv = (const float*)(ws + HV_OFF);
  int gid = blockIdx.x * 256 + threadIdx.x;
  int row = gid >> 6;
  int d = (gid & 63) * 4;
  int b = row >> 12;
  float4 c4 = ((const float4*)context)[gid];
  float4 h4 = *(const float4*)(hv + b * DD + d);
  float4 r;
  r.x = c4.x * h4.x; r.y = c4.y * h4.y; r.z = c4.z * h4.z; r.w = c4.w * h4.w;
  *(float4*)(out + (size_t)row * TQ + 3 * DD + d) = r;
}

extern "C" void kernel_launch(void* const* d_in, const int* in_sizes, int n_in,
                              void* d_out, int out_size, void* d_ws, size_t ws_size,
                              hipStream_t stream) {
  (void)in_sizes; (void)n_in; (void)out_size; (void)ws_size;
  const float* context  = (const float*)d_in[0];
  const float* question = (const float*)d_in[1];
  const float* w        = (const float*)d_in[2];
  float* out = (float*)d_out;
  char* ws = (char*)d_ws;

  k_qprep<<<NB * NJT, 256, 0, stream>>>(question, w, ws);
  k_main<<<NB * (TC / 64), 256, 0, stream>>>(context, w, ws,
                                             (float*)(ws + BV_OFF), out);
  hipMemsetAsync(ws + HV_OFF, 0, NB * DD * sizeof(float), stream);
  k_hred<<<NB * 32, 256, 0, stream>>>(context, ws, (float*)(ws + HV_OFF));
  k_final<<<(NB * TC * DD / 4) / 256, 256, 0, stream>>>(context, ws, out);
}

// Round 2
// 224.973 us; speedup vs baseline: 1.0348x; 1.0348x over previous
//
#include <hip/hip_runtime.h>
#include <hip/hip_bf16.h>
#include <stdint.h>
#include <stddef.h>

// BiAttentionLayer: B=8, Tc=4096, Tq=1024, D=256, fp32 in/out.
// Math: s_c (w1) cancels in softmax/U/b. exp without running max is safe
// (|S+s_q| <= ~15). b[i] = exp(m)/l.
// Round-3: 2-phase pipeline (global_load_lds dbuf, 1 full barrier/iter).
// Round-4 (this round): d-split mm2 — wave w computes U[all 64 i][its 64 d]
// instead of U[its 16 i][all 256 d]. Cuts per-CU qx (mm2 B) L1/L2 traffic 4x
// (was 8x-redundant: every wave read the whole 16 KiB tile). P is shared
// through block LDS; mid-loop barrier is lgkm-only (raw s_barrier) so the
// async qa staging stays in flight until the loop-end __syncthreads.

#define NB 8
#define TC 4096
#define TQ 1024
#define DD 256
#define JT 32
#define NJT (TQ / JT)

typedef __attribute__((ext_vector_type(4)))  float  f32x4v;
typedef __attribute__((ext_vector_type(8)))  __bf16 bf16x8v;
typedef __attribute__((ext_vector_type(4)))  __bf16 bf16x4v;

// workspace layout (bytes)
#define QA_OFF   0                              // bf16 frag-order for mm1 A: [b][it][jm][c][L][8]  (4 MiB)
#define QX_OFF   (QA_OFF + NB*NJT*16*1024)      // bf16 frag-order for mm2 B: [b][it][mt][L][8]     (4 MiB)
#define SQ_OFF   (QX_OFF + NB*NJT*16*1024)      // f32 [NB][TQ]
#define BV_OFF   (SQ_OFF + NB*TQ*4)             // f32 [NB][TC]
#define HV_OFF   (BV_OFF + NB*TC*4)             // f32 [NB][DD]

__device__ __forceinline__ void async_cp16(const void* g, void* l) {
  __builtin_amdgcn_global_load_lds(
      (const __attribute__((address_space(1))) void*)g,
      (__attribute__((address_space(3))) void*)l, 16, 0, 0);
}

// ---------------- kernel 0: question preprocessing ----------------
__global__ __launch_bounds__(256) void k_qprep(const float* __restrict__ question,
                                               const float* __restrict__ w,
                                               char* __restrict__ ws) {
  uint4* qa = (uint4*)(ws + QA_OFF);
  uint4* qx = (uint4*)(ws + QX_OFF);
  float* sq = (float*)(ws + SQ_OFF);
  __shared__ __align__(16) __bf16 T[32][264];   // 528 B row stride (16-aligned)

  int bx = blockIdx.x;
  int b = bx >> 5, it = bx & 31;
  int t = threadIdx.x;
  int j = t >> 3;         // 0..31
  int seg = t & 7;        // d segment of 32

  const float* qrow = question + ((size_t)(b * TQ + it * JT + j)) * DD + seg * 32;
  const float* w2 = w + DD;

  float part = 0.f;
#pragma unroll
  for (int k = 0; k < 8; ++k) {
    float4 v  = *(const float4*)(qrow + 4 * k);
    float4 wv = *(const float4*)(w2 + seg * 32 + 4 * k);
    part += v.x * wv.x + v.y * wv.y + v.z * wv.z + v.w * wv.w;
    bf16x4v pk = {(__bf16)v.x, (__bf16)v.y, (__bf16)v.z, (__bf16)v.w};
    *(bf16x4v*)&T[j][seg * 32 + 4 * k] = pk;
  }
  part += __shfl_xor(part, 1);
  part += __shfl_xor(part, 2);
  part += __shfl_xor(part, 4);
  if (seg == 0) sq[b * TQ + it * JT + j] = part;
  __syncthreads();

  // qa chunks: ch = (jm*8+c)*64 + L ; element T[16*jm + (L&15)][32*c + 8*(L>>4) + o]
#pragma unroll
  for (int p = 0; p < 4; ++p) {
    int ch = t + 256 * p;
    int L = ch & 63, cc = ch >> 6;
    int jm = cc >> 3, c = cc & 7;
    int nh = L & 15, qh = L >> 4;
    uint4 v = *(const uint4*)&T[16 * jm + nh][32 * c + 8 * qh];
    qa[(size_t)(b * NJT + it) * 1024 + ch] = v;
  }
  // qx chunks: ch = mt*64 + L ; element T[8*(L>>4) + o][16*mt + (L&15)]
#pragma unroll
  for (int p = 0; p < 4; ++p) {
    int ch = t + 256 * p;
    int L = ch & 63, mt = ch >> 6;
    int nh = L & 15, qh = L >> 4;
    __bf16 e[8];
#pragma unroll
    for (int o = 0; o < 8; ++o) e[o] = T[8 * qh + o][16 * mt + nh];
    qx[(size_t)(b * NJT + it) * 1024 + ch] = *(const uint4*)e;
  }
}

// ---------------- kernel 1: fused scores+softmax+U + G chunks 0/1/2 ----------------
// 512 blocks x 256 thr (4 waves). Block owns 64 i.
// mm1: wave w computes S^T[32j][16i_w] (A = staged qa frags, B = cw3 regs)
// mm2 (d-split): wave w computes U[64i][64d_w] += P . qx  (A = block P via LDS,
//   B = 4 frag loads/wave from L2, prefetched before the P barrier)
__global__ __launch_bounds__(256, 2) void k_main(const float* __restrict__ context,
                                                 const float* __restrict__ w,
                                                 const char* __restrict__ ws,
                                                 float* __restrict__ bv_out,
                                                 float* __restrict__ out) {
  const uint4*  qa = (const uint4*)(ws + QA_OFF);
  const __bf16* qx = (const __bf16*)(ws + QX_OFF);
  const float*  sq = (const float*)(ws + SQ_OFF);

  __shared__ __align__(16) __bf16 qa_lds[2][8192];   // 2 x 16 KiB double buffer
  __shared__ __align__(16) __bf16 pa_lds[4][16][40]; // block P, [mi][nh][j] (80 B rows)
  __shared__ __align__(16) float  sq_all[TQ];        // all s_q for this batch (4 KiB)
  __shared__ __align__(16) float  rinv_lds[64];

  int bx = blockIdx.x;
  int b = bx & 7;                 // XCD-affine batch mapping
  int ig = bx >> 3;               // 0..63
  int t = threadIdx.x;
  int wv = t >> 6;
  int lane = t & 63;
  int nh = lane & 15;             // col index (i for mm1 out, d for mm2 out)
  int qh = lane >> 4;             // quad
  int i0w = ig * 64 + wv * 16;    // wave's i-tile for mm1 (== m-tile wv of block)

  const uint4* qa_b = qa + (size_t)b * NJT * 1024;
  const __bf16* qx_b = qx + (size_t)b * NJT * 8192;
  const float* sqb = sq + b * TQ;

  // cw3 B-frags: B[k=d][n=i] = context[i0w+nh][d]*w3[d], d = 32c + 8qh + o
  bf16x8v cw3f[8];
  {
    const float* crow = context + ((size_t)(b * TC + i0w + nh)) * DD;
    const float* w3 = w + 2 * DD;
#pragma unroll
    for (int c = 0; c < 8; ++c) {
      int d0 = 32 * c + 8 * qh;
      float4 f0 = *(const float4*)(crow + d0);
      float4 f1 = *(const float4*)(crow + d0 + 4);
      float4 g0 = *(const float4*)(w3 + d0);
      float4 g1 = *(const float4*)(w3 + d0 + 4);
      bf16x8v fr;
      fr[0] = (__bf16)(f0.x * g0.x); fr[1] = (__bf16)(f0.y * g0.y);
      fr[2] = (__bf16)(f0.z * g0.z); fr[3] = (__bf16)(f0.w * g0.w);
      fr[4] = (__bf16)(f1.x * g1.x); fr[5] = (__bf16)(f1.y * g1.y);
      fr[6] = (__bf16)(f1.z * g1.z); fr[7] = (__bf16)(f1.w * g1.w);
      cw3f[c] = fr;
    }
  }

  // prologue: stage s_q for the whole batch (4 KiB) + qa tile 0 into buf 0
  {
    ((float4*)sq_all)[t] = ((const float4*)sqb)[t];
    const uint4* src = qa_b;  // tile 0
#pragma unroll
    for (int p = 0; p < 4; ++p) {
      int cb = wv * 64 + p * 256;                 // wave-uniform chunk base
      async_cp16(src + cb + lane, &qa_lds[0][(size_t)cb * 8]);
    }
  }

  f32x4v U[16];   // U[mi*4+nt]: rows i = mi*16+4qh+r, cols d = wv*64+nt*16+nh
#pragma unroll
  for (int k = 0; k < 16; ++k) U[k] = (f32x4v){0.f, 0.f, 0.f, 0.f};
  float m_run = -1e30f, l_run = 0.f;

  __syncthreads();   // drains vmcnt(0): tile 0 staged, sq_all visible

  for (int itq = 0; itq < NJT; ++itq) {
    int cur = itq & 1;

    // stage NEXT qa tile into the spare buffer; stays in flight across the
    // whole iteration (mid-loop barrier is lgkm-only), drained at loop bottom.
    if (itq + 1 < NJT) {
      const uint4* src = qa_b + (size_t)(itq + 1) * 1024;
#pragma unroll
      for (int p = 0; p < 4; ++p) {
        int cb = wv * 64 + p * 256;
        async_cp16(src + cb + lane, &qa_lds[cur ^ 1][(size_t)cb * 8]);
      }
    }

    // mm1: S^T[32j][16i_w], K=256 in 8 chunks of 32
    f32x4v S0 = {0.f, 0.f, 0.f, 0.f}, S1 = {0.f, 0.f, 0.f, 0.f};
#pragma unroll
    for (int c = 0; c < 8; ++c) {
      bf16x8v a0 = *(const bf16x8v*)&qa_lds[cur][((0 * 8 + c) * 64 + lane) * 8];
      bf16x8v a1 = *(const bf16x8v*)&qa_lds[cur][((1 * 8 + c) * 64 + lane) * 8];
      S0 = __builtin_amdgcn_mfma_f32_16x16x32_bf16(a0, cw3f[c], S0, 0, 0, 0);
      S1 = __builtin_amdgcn_mfma_f32_16x16x32_bf16(a1, cw3f[c], S1, 0, 0, 0);
    }

    // prefetch this wave's 4 qx B-frags (d-slice [wv*64, wv*64+64)) — L2
    // latency hides under softmax + barrier.
    bf16x8v bqr[4];
    {
      const __bf16* qxt = qx_b + (size_t)itq * 8192 + lane * 8;
#pragma unroll
      for (int nt = 0; nt < 4; ++nt)
        bqr[nt] = *(const bf16x8v*)(qxt + (size_t)(wv * 4 + nt) * 512);
    }

    // P = exp(S + s_q): lane holds (i=nh, j = 16jm + 4qh + r)
    float4 sq0 = *(const float4*)&sq_all[itq * JT + 4 * qh];
    float4 sq1 = *(const float4*)&sq_all[itq * JT + 16 + 4 * qh];
    float e0 = __expf(S0[0] + sq0.x), e1 = __expf(S0[1] + sq0.y);
    float e2 = __expf(S0[2] + sq0.z), e3 = __expf(S0[3] + sq0.w);
    float f0 = __expf(S1[0] + sq1.x), f1 = __expf(S1[1] + sq1.y);
    float f2 = __expf(S1[2] + sq1.z), f3 = __expf(S1[3] + sq1.w);
    float v0 = fmaxf(fmaxf(S0[0] + sq0.x, S0[1] + sq0.y), fmaxf(S0[2] + sq0.z, S0[3] + sq0.w));
    float v1 = fmaxf(fmaxf(S1[0] + sq1.x, S1[1] + sq1.y), fmaxf(S1[2] + sq1.z, S1[3] + sq1.w));
    m_run = fmaxf(m_run, fmaxf(v0, v1));
    l_run += ((e0 + e1) + (e2 + e3)) + ((f0 + f1) + (f2 + f3));

    // write P to block LDS in mm2-A order: pa[mi=wv][i=nh][j]
    bf16x4v pk0 = {(__bf16)e0, (__bf16)e1, (__bf16)e2, (__bf16)e3};
    bf16x4v pk1 = {(__bf16)f0, (__bf16)f1, (__bf16)f2, (__bf16)f3};
    *(bf16x4v*)&pa_lds[wv][nh][4 * qh]      = pk0;
    *(bf16x4v*)&pa_lds[wv][nh][16 + 4 * qh] = pk1;

    // lgkm-only barrier: P visible to all waves; async staging NOT drained.
    asm volatile("s_waitcnt lgkmcnt(0)\n\ts_barrier" ::: "memory");

    // mm2 (d-split): U[64i][64d_w] += P[64i][32j] . qx[32j][64d_w]
#pragma unroll
    for (int mi = 0; mi < 4; ++mi) {
      bf16x8v af = *(const bf16x8v*)&pa_lds[mi][nh][8 * qh];
#pragma unroll
      for (int nt = 0; nt < 4; ++nt)
        U[mi * 4 + nt] = __builtin_amdgcn_mfma_f32_16x16x32_bf16(af, bqr[nt], U[mi * 4 + nt], 0, 0, 0);
    }

    // full barrier: next tile staged (vmcnt) + all P reads done before overwrite.
    __syncthreads();
  }

  // reduce l, m across quads (lanes with same nh) — valid for i = i0w + nh
  float lo = l_run + __shfl_xor(l_run, 16);
  lo += __shfl_xor(lo, 32);
  float mo = fmaxf(m_run, __shfl_xor(m_run, 16));
  mo = fmaxf(mo, __shfl_xor(mo, 32));
  float rinv = 1.0f / lo;
  if (lane < 16) {
    bv_out[b * TC + i0w + nh] = __expf(mo) * rinv;
    rinv_lds[wv * 16 + nh] = rinv;
  }
  __syncthreads();

  // epilogue: wave wv owns d in [wv*64, wv*64+64) for all 64 block rows.
  // U[mi*4+nt][r]: row i = ig*64 + mi*16 + 4qh + r, col d = wv*64 + nt*16 + nh
#pragma unroll
  for (int mi = 0; mi < 4; ++mi) {
#pragma unroll
    for (int r = 0; r < 4; ++r) {
      int row = ig * 64 + mi * 16 + 4 * qh + r;
      float rv = rinv_lds[mi * 16 + 4 * qh + r];
      const float* crow = context + ((size_t)(b * TC + row)) * DD;
      float* orow = out + ((size_t)(b * TC + row)) * (4 * DD);
#pragma unroll
      for (int nt = 0; nt < 4; ++nt) {
        int d = wv * 64 + nt * 16 + nh;
        float c = crow[d];
        float u = U[mi * 4 + nt][r] * rv;
        orow[d] = c;
        orow[DD + d] = u;
        orow[2 * DD + d] = c * u;
      }
    }
  }
}

// ---------------- kernel 2: h[b][d] = sum_i b[i] * context[b][i][d] ----------------
__global__ __launch_bounds__(256) void k_hred(const float* __restrict__ context,
                                              const char* __restrict__ ws,
                                              float* __restrict__ hv) {
  const float* bv = (const float*)(ws + BV_OFF);
  __shared__ float bsh[128];
  int bx = blockIdx.x;
  int b = bx >> 5, ch = bx & 31;
  int i0 = ch * 128;
  int t = threadIdx.x;
  if (t < 128) bsh[t] = bv[b * TC + i0 + t];
  __syncthreads();
  float acc = 0.f;
  const float* cp = context + ((size_t)(b * TC + i0)) * DD + t;
#pragma unroll 4
  for (int r = 0; r < 128; ++r) acc += bsh[r] * cp[(size_t)r * DD];
  atomicAdd(&hv[b * DD + t], acc);
}

// ---------------- kernel 3: G chunk 3 = context * H ----------------
__global__ __launch_bounds__(256) void k_final(const float* __restrict__ context,
                                               const char* __restrict__ ws,
                                               float* __restrict__ out) {
  const float* hv = (const float*)(ws + HV_OFF);
  int gid = blockIdx.x * 256 + threadIdx.x;
  int row = gid >> 6;
  int d = (gid & 63) * 4;
  int b = row >> 12;
  float4 c4 = ((const float4*)context)[gid];
  float4 h4 = *(const float4*)(hv + b * DD + d);
  float4 r;
  r.x = c4.x * h4.x; r.y = c4.y * h4.y; r.z = c4.z * h4.z; r.w = c4.w * h4.w;
  *(float4*)(out + (size_t)row * TQ + 3 * DD + d) = r;
}

extern "C" void kernel_launch(void* const* d_in, const int* in_sizes, int n_in,
                              void* d_out, int out_size, void* d_ws, size_t ws_size,
                              hipStream_t stream) {
  (void)in_sizes; (void)n_in; (void)out_size; (void)ws_size;
  const float* context  = (const float*)d_in[0];
  const float* question = (const float*)d_in[1];
  const float* w        = (const float*)d_in[2];
  float* out = (float*)d_out;
  char* ws = (char*)d_ws;

  k_qprep<<<NB * NJT, 256, 0, stream>>>(question, w, ws);
  k_main<<<NB * (TC / 64), 256, 0, stream>>>(context, w, ws,
                                             (float*)(ws + BV_OFF), out);
  hipMemsetAsync(ws + HV_OFF, 0, NB * DD * sizeof(float), stream);
  k_hred<<<NB * 32, 256, 0, stream>>>(context, ws, (float*)(ws + HV_OFF));
  k_final<<<(NB * TC * DD / 4) / 256, 256, 0, stream>>>(context, ws, out);
}

// Round 3
// 212.607 us; speedup vs baseline: 1.0950x; 1.0582x over previous
//
#include <hip/hip_runtime.h>
#include <hip/hip_bf16.h>
#include <stdint.h>
#include <stddef.h>

// BiAttentionLayer: B=8, Tc=4096, Tq=1024, D=256, fp32 in/out.
// Math: s_c (w1) cancels in softmax/U/b. exp without running max is safe
// (|S+s_q| <= ~15). b[i] = exp(m)/l.
// Round-3: 2-phase pipeline (global_load_lds dbuf, 1 full barrier/iter).
// Round-4: d-split mm2 (wave = 64-d slice of U, P shared via LDS).
// Round-5 (this round):
//   * hybrid 2x2 mm1 split: wave (wi,wj) computes S^T[16j of half wj][32i of
//     half wi] -> each wave reads only its 8 KiB j-slice of qa (was: all 4
//     waves read the full 16 KiB; LDS-BW was the measured limiter at
//     ~200 KiB/CU/iter ~= 1790 cy ~= observed iter time).
//   * h-reduction fused into k_main epilogue (atomicAdd per d) -> k_hred
//     and its 128 MB context re-read deleted.
//   * qx B-frag prefetch hoisted to top of iteration (overlaps mm1 too).

#define NB 8
#define TC 4096
#define TQ 1024
#define DD 256
#define JT 32
#define NJT (TQ / JT)

typedef __attribute__((ext_vector_type(4)))  float  f32x4v;
typedef __attribute__((ext_vector_type(8)))  __bf16 bf16x8v;
typedef __attribute__((ext_vector_type(4)))  __bf16 bf16x4v;

// workspace layout (bytes)
#define QA_OFF   0                              // bf16 frag-order for mm1 A: [b][it][jm][c][L][8]  (4 MiB)
#define QX_OFF   (QA_OFF + NB*NJT*16*1024)      // bf16 frag-order for mm2 B: [b][it][mt][L][8]     (4 MiB)
#define SQ_OFF   (QX_OFF + NB*NJT*16*1024)      // f32 [NB][TQ]
#define HV_OFF   (SQ_OFF + NB*TQ*4)             // f32 [NB][DD]

__device__ __forceinline__ void async_cp16(const void* g, void* l) {
  __builtin_amdgcn_global_load_lds(
      (const __attribute__((address_space(1))) void*)g,
      (__attribute__((address_space(3))) void*)l, 16, 0, 0);
}

// ---------------- kernel 0: question preprocessing ----------------
__global__ __launch_bounds__(256) void k_qprep(const float* __restrict__ question,
                                               const float* __restrict__ w,
                                               char* __restrict__ ws) {
  uint4* qa = (uint4*)(ws + QA_OFF);
  uint4* qx = (uint4*)(ws + QX_OFF);
  float* sq = (float*)(ws + SQ_OFF);
  __shared__ __align__(16) __bf16 T[32][264];   // 528 B row stride (16-aligned)

  int bx = blockIdx.x;
  int b = bx >> 5, it = bx & 31;
  int t = threadIdx.x;
  int j = t >> 3;         // 0..31
  int seg = t & 7;        // d segment of 32

  const float* qrow = question + ((size_t)(b * TQ + it * JT + j)) * DD + seg * 32;
  const float* w2 = w + DD;

  float part = 0.f;
#pragma unroll
  for (int k = 0; k < 8; ++k) {
    float4 v  = *(const float4*)(qrow + 4 * k);
    float4 wv = *(const float4*)(w2 + seg * 32 + 4 * k);
    part += v.x * wv.x + v.y * wv.y + v.z * wv.z + v.w * wv.w;
    bf16x4v pk = {(__bf16)v.x, (__bf16)v.y, (__bf16)v.z, (__bf16)v.w};
    *(bf16x4v*)&T[j][seg * 32 + 4 * k] = pk;
  }
  part += __shfl_xor(part, 1);
  part += __shfl_xor(part, 2);
  part += __shfl_xor(part, 4);
  if (seg == 0) sq[b * TQ + it * JT + j] = part;
  __syncthreads();

  // qa chunks: ch = (jm*8+c)*64 + L ; element T[16*jm + (L&15)][32*c + 8*(L>>4) + o]
#pragma unroll
  for (int p = 0; p < 4; ++p) {
    int ch = t + 256 * p;
    int L = ch & 63, cc = ch >> 6;
    int jm = cc >> 3, c = cc & 7;
    int nh = L & 15, qh = L >> 4;
    uint4 v = *(const uint4*)&T[16 * jm + nh][32 * c + 8 * qh];
    qa[(size_t)(b * NJT + it) * 1024 + ch] = v;
  }
  // qx chunks: ch = mt*64 + L ; element T[8*(L>>4) + o][16*mt + (L&15)]
#pragma unroll
  for (int p = 0; p < 4; ++p) {
    int ch = t + 256 * p;
    int L = ch & 63, mt = ch >> 6;
    int nh = L & 15, qh = L >> 4;
    __bf16 e[8];
#pragma unroll
    for (int o = 0; o < 8; ++o) e[o] = T[8 * qh + o][16 * mt + nh];
    qx[(size_t)(b * NJT + it) * 1024 + ch] = *(const uint4*)e;
  }
}

// ---------------- kernel 1: fused scores+softmax+U+h + G chunks 0/1/2 ----------------
// 512 blocks x 256 thr (4 waves). Block owns 64 i.
// mm1 (2x2 split): wave (wi,wj) computes S^T[16j (jm=wj)][32i (it=2wi,2wi+1)]
//   A = its 8 KiB j-slice of staged qa, B = cw3 regs for 2 i-tiles.
// mm2 (d-split): wave wv computes U[64i][64d_wv] += P . qx (A = block P via LDS,
//   B = 4 frag loads/wave from L2, prefetched at top of iteration)
// epilogue: writes G chunks 0/1/2 and atomically accumulates h[b][d].
__global__ __launch_bounds__(256, 2) void k_main(const float* __restrict__ context,
                                                 const float* __restrict__ w,
                                                 const char* __restrict__ ws,
                                                 float* __restrict__ hv,
                                                 float* __restrict__ out) {
  const uint4*  qa = (const uint4*)(ws + QA_OFF);
  const __bf16* qx = (const __bf16*)(ws + QX_OFF);
  const float*  sq = (const float*)(ws + SQ_OFF);

  __shared__ __align__(16) __bf16 qa_lds[2][8192];   // 2 x 16 KiB double buffer
  __shared__ __align__(16) __bf16 pa_lds[4][16][40]; // block P, [it][nh][j] (80 B rows)
  __shared__ __align__(16) float  sq_all[TQ];        // all s_q for this batch (4 KiB)
  __shared__ __align__(16) float  red_lm[2][4][16][2]; // [wj][it][nh][{l,m}]
  __shared__ __align__(16) float  rinv_lds[64];
  __shared__ __align__(16) float  bvv_lds[64];

  int bx = blockIdx.x;
  int b = bx & 7;                 // XCD-affine batch mapping
  int ig = bx >> 3;               // 0..63
  int t = threadIdx.x;
  int wv = t >> 6;
  int lane = t & 63;
  int wi = wv >> 1;               // i-half for mm1
  int wj = wv & 1;                // j-half for mm1
  int it0 = 2 * wi, it1 = 2 * wi + 1;
  int nh = lane & 15;             // col index (i for mm1 out, d for mm2 out)
  int qh = lane >> 4;             // quad

  const uint4* qa_b = qa + (size_t)b * NJT * 1024;
  const __bf16* qx_b = qx + (size_t)b * NJT * 8192;
  const float* sqb = sq + b * TQ;

  // cw3 B-frags for i-tiles it0, it1: B[k=d][n=i] = context[i][d]*w3[d]
  bf16x8v cw3f0[8], cw3f1[8];
  {
    const float* crow0 = context + ((size_t)(b * TC + ig * 64 + 32 * wi + nh)) * DD;
    const float* crow1 = crow0 + 16 * DD;
    const float* w3 = w + 2 * DD;
#pragma unroll
    for (int c = 0; c < 8; ++c) {
      int d0 = 32 * c + 8 * qh;
      float4 g0 = *(const float4*)(w3 + d0);
      float4 g1 = *(const float4*)(w3 + d0 + 4);
      float4 f0 = *(const float4*)(crow0 + d0);
      float4 f1 = *(const float4*)(crow0 + d0 + 4);
      bf16x8v fr;
      fr[0] = (__bf16)(f0.x * g0.x); fr[1] = (__bf16)(f0.y * g0.y);
      fr[2] = (__bf16)(f0.z * g0.z); fr[3] = (__bf16)(f0.w * g0.w);
      fr[4] = (__bf16)(f1.x * g1.x); fr[5] = (__bf16)(f1.y * g1.y);
      fr[6] = (__bf16)(f1.z * g1.z); fr[7] = (__bf16)(f1.w * g1.w);
      cw3f0[c] = fr;
      float4 h0 = *(const float4*)(crow1 + d0);
      float4 h1 = *(const float4*)(crow1 + d0 + 4);
      bf16x8v hr;
      hr[0] = (__bf16)(h0.x * g0.x); hr[1] = (__bf16)(h0.y * g0.y);
      hr[2] = (__bf16)(h0.z * g0.z); hr[3] = (__bf16)(h0.w * g0.w);
      hr[4] = (__bf16)(h1.x * g1.x); hr[5] = (__bf16)(h1.y * g1.y);
      hr[6] = (__bf16)(h1.z * g1.z); hr[7] = (__bf16)(h1.w * g1.w);
      cw3f1[c] = hr;
    }
  }

  // prologue: stage s_q for the whole batch (4 KiB) + qa tile 0 into buf 0
  {
    ((float4*)sq_all)[t] = ((const float4*)sqb)[t];
    const uint4* src = qa_b;  // tile 0
#pragma unroll
    for (int p = 0; p < 4; ++p) {
      int cb = wv * 64 + p * 256;                 // wave-uniform chunk base
      async_cp16(src + cb + lane, &qa_lds[0][(size_t)cb * 8]);
    }
  }

  f32x4v U[16];   // U[mi*4+nt]: rows i = mi*16+4qh+r, cols d = wv*64+nt*16+nh
#pragma unroll
  for (int k = 0; k < 16; ++k) U[k] = (f32x4v){0.f, 0.f, 0.f, 0.f};
  float m0_run = -1e30f, l0_run = 0.f;
  float m1_run = -1e30f, l1_run = 0.f;

  __syncthreads();   // drains vmcnt(0): tile 0 staged, sq_all visible

  for (int itq = 0; itq < NJT; ++itq) {
    int cur = itq & 1;

    // prefetch this wave's 4 qx B-frags (d-slice [wv*64, wv*64+64)) — issued
    // first: L2 latency hides under mm1 + softmax + barrier.
    bf16x8v bqr[4];
    {
      const __bf16* qxt = qx_b + (size_t)itq * 8192 + lane * 8;
#pragma unroll
      for (int nt = 0; nt < 4; ++nt)
        bqr[nt] = *(const bf16x8v*)(qxt + (size_t)(wv * 4 + nt) * 512);
    }

    // stage NEXT qa tile into the spare buffer; stays in flight across the
    // whole iteration (mid-loop barrier is lgkm-only), drained at loop bottom.
    if (itq + 1 < NJT) {
      const uint4* src = qa_b + (size_t)(itq + 1) * 1024;
#pragma unroll
      for (int p = 0; p < 4; ++p) {
        int cb = wv * 64 + p * 256;
        async_cp16(src + cb + lane, &qa_lds[cur ^ 1][(size_t)cb * 8]);
      }
    }

    // mm1: S^T[16j (jm=wj)][32 i (it0,it1)], K=256 in 8 chunks of 32.
    // Each wave reads only its 8 KiB j-slice of the staged tile.
    f32x4v S0 = {0.f, 0.f, 0.f, 0.f}, S1 = {0.f, 0.f, 0.f, 0.f};
#pragma unroll
    for (int c = 0; c < 8; ++c) {
      bf16x8v ac = *(const bf16x8v*)&qa_lds[cur][((wj * 8 + c) * 64 + lane) * 8];
      S0 = __builtin_amdgcn_mfma_f32_16x16x32_bf16(ac, cw3f0[c], S0, 0, 0, 0);
      S1 = __builtin_amdgcn_mfma_f32_16x16x32_bf16(ac, cw3f1[c], S1, 0, 0, 0);
    }

    // P = exp(S + s_q): lane holds (i=nh of it, j = 16wj + 4qh + r)
    float4 sqv = *(const float4*)&sq_all[itq * JT + 16 * wj + 4 * qh];
    float a0 = S0[0] + sqv.x, a1 = S0[1] + sqv.y, a2 = S0[2] + sqv.z, a3 = S0[3] + sqv.w;
    float b0 = S1[0] + sqv.x, b1 = S1[1] + sqv.y, b2 = S1[2] + sqv.z, b3 = S1[3] + sqv.w;
    float e0 = __expf(a0), e1 = __expf(a1), e2 = __expf(a2), e3 = __expf(a3);
    float f0 = __expf(b0), f1 = __expf(b1), f2 = __expf(b2), f3 = __expf(b3);
    m0_run = fmaxf(m0_run, fmaxf(fmaxf(a0, a1), fmaxf(a2, a3)));
    m1_run = fmaxf(m1_run, fmaxf(fmaxf(b0, b1), fmaxf(b2, b3)));
    l0_run += (e0 + e1) + (e2 + e3);
    l1_run += (f0 + f1) + (f2 + f3);

    // write P to block LDS in mm2-A order: pa[it][i=nh][j = 16wj + 4qh + r]
    bf16x4v pk0 = {(__bf16)e0, (__bf16)e1, (__bf16)e2, (__bf16)e3};
    bf16x4v pk1 = {(__bf16)f0, (__bf16)f1, (__bf16)f2, (__bf16)f3};
    *(bf16x4v*)&pa_lds[it0][nh][16 * wj + 4 * qh] = pk0;
    *(bf16x4v*)&pa_lds[it1][nh][16 * wj + 4 * qh] = pk1;

    // lgkm-only barrier: P visible to all waves; async staging NOT drained.
    asm volatile("s_waitcnt lgkmcnt(0)\n\ts_barrier" ::: "memory");

    // mm2 (d-split): U[64i][64d_wv] += P[64i][32j] . qx[32j][64d_wv]
#pragma unroll
    for (int mi = 0; mi < 4; ++mi) {
      bf16x8v af = *(const bf16x8v*)&pa_lds[mi][nh][8 * qh];
#pragma unroll
      for (int nt = 0; nt < 4; ++nt)
        U[mi * 4 + nt] = __builtin_amdgcn_mfma_f32_16x16x32_bf16(af, bqr[nt], U[mi * 4 + nt], 0, 0, 0);
    }

    // full barrier: next tile staged (vmcnt) + all P reads done before overwrite.
    __syncthreads();
  }

  // quad-reduce l, m over qh (lanes with same nh): partials for this wave's
  // j-half of i-tiles it0, it1.
  float lo0 = l0_run + __shfl_xor(l0_run, 16); lo0 += __shfl_xor(lo0, 32);
  float lo1 = l1_run + __shfl_xor(l1_run, 16); lo1 += __shfl_xor(lo1, 32);
  float mo0 = fmaxf(m0_run, __shfl_xor(m0_run, 16)); mo0 = fmaxf(mo0, __shfl_xor(mo0, 32));
  float mo1 = fmaxf(m1_run, __shfl_xor(m1_run, 16)); mo1 = fmaxf(mo1, __shfl_xor(mo1, 32));
  if (lane < 16) {
    red_lm[wj][it0][nh][0] = lo0; red_lm[wj][it0][nh][1] = mo0;
    red_lm[wj][it1][nh][0] = lo1; red_lm[wj][it1][nh][1] = mo1;
  }
  __syncthreads();
  if (t < 64) {
    int it = t >> 4, n = t & 15;
    float l = red_lm[0][it][n][0] + red_lm[1][it][n][0];
    float m = fmaxf(red_lm[0][it][n][1], red_lm[1][it][n][1]);
    float ri = 1.0f / l;
    rinv_lds[t] = ri;
    bvv_lds[t] = __expf(m) * ri;    // b[i] = max(A_row) = exp(m)/l
  }
  __syncthreads();

  // epilogue: wave wv owns d in [wv*64, wv*64+64) for all 64 block rows.
  // U[mi*4+nt][r]: row i = ig*64 + mi*16 + 4qh + r, col d = wv*64 + nt*16 + nh
  // Also accumulate h[d] = sum_i b[i]*context[i][d] for this block's rows.
  float hacc[4] = {0.f, 0.f, 0.f, 0.f};
#pragma unroll
  for (int mi = 0; mi < 4; ++mi) {
#pragma unroll
    for (int r = 0; r < 4; ++r) {
      int rl = mi * 16 + 4 * qh + r;
      int row = ig * 64 + rl;
      float rv = rinv_lds[rl];
      float bb = bvv_lds[rl];
      const float* crow = context + ((size_t)(b * TC + row)) * DD;
      float* orow = out + ((size_t)(b * TC + row)) * (4 * DD);
#pragma unroll
      for (int nt = 0; nt < 4; ++nt) {
        int d = wv * 64 + nt * 16 + nh;
        float c = crow[d];
        float u = U[mi * 4 + nt][r] * rv;
        orow[d] = c;
        orow[DD + d] = u;
        orow[2 * DD + d] = c * u;
        hacc[nt] += bb * c;
      }
    }
  }
  // reduce hacc over qh (4 lanes share each d), one atomic per (d) per block
#pragma unroll
  for (int nt = 0; nt < 4; ++nt) {
    float h = hacc[nt] + __shfl_xor(hacc[nt], 16);
    h += __shfl_xor(h, 32);
    if (qh == 0) atomicAdd(&hv[b * DD + wv * 64 + nt * 16 + nh], h);
  }
}

// ---------------- kernel 3: G chunk 3 = context * H ----------------
__global__ __launch_bounds__(256) void k_final(const float* __restrict__ context,
                                               const char* __restrict__ ws,
                                               float* __restrict__ out) {
  const float* hv = (const float*)(ws + HV_OFF);
  int gid = blockIdx.x * 256 + threadIdx.x;
  int row = gid >> 6;
  int d = (gid & 63) * 4;
  int b = row >> 12;
  float4 c4 = ((const float4*)context)[gid];
  float4 h4 = *(const float4*)(hv + b * DD + d);
  float4 r;
  r.x = c4.x * h4.x; r.y = c4.y * h4.y; r.z = c4.z * h4.z; r.w = c4.w * h4.w;
  *(float4*)(out + (size_t)row * TQ + 3 * DD + d) = r;
}

extern "C" void kernel_launch(void* const* d_in, const int* in_sizes, int n_in,
                              void* d_out, int out_size, void* d_ws, size_t ws_size,
                              hipStream_t stream) {
  (void)in_sizes; (void)n_in; (void)out_size; (void)ws_size;
  const float* context  = (const float*)d_in[0];
  const float* question = (const float*)d_in[1];
  const float* w        = (const float*)d_in[2];
  float* out = (float*)d_out;
  char* ws = (char*)d_ws;

  k_qprep<<<NB * NJT, 256, 0, stream>>>(question, w, ws);
  hipMemsetAsync(ws + HV_OFF, 0, NB * DD * sizeof(float), stream);
  k_main<<<NB * (TC / 64), 256, 0, stream>>>(context, w, ws,
                                             (float*)(ws + HV_OFF), out);
  k_final<<<(NB * TC * DD / 4) / 256, 256, 0, stream>>>(context, ws, out);
}

// Round 4
// 211.981 us; speedup vs baseline: 1.0982x; 1.0030x over previous
//
#include <hip/hip_runtime.h>
#include <hip/hip_bf16.h>
#include <stdint.h>
#include <stddef.h>

// BiAttentionLayer: B=8, Tc=4096, Tq=1024, D=256, fp32 in/out.
// Math: s_c (w1) cancels in softmax/U/b. exp without running max is safe
// (|S+s_q| <= ~15). b[i] = exp(m)/l.
// Round-3: 2-phase pipeline (global_load_lds dbuf, 1 full barrier/iter... plus
//          a mid-loop lgkm barrier for P sharing).
// Round-4: d-split mm2 (wave = 64-d slice of U, P shared via LDS).
// Round-5: hybrid 2x2 mm1 split; h-reduction fused into epilogue.
// Round-6 (this round): deferred-mm2 software pipeline (T15 style) —
//   mm2 at iter t consumes P(t-1) from a pa double buffer (visible since the
//   previous barrier) while mm1 computes P(t). Deletes the mid-loop lgkm
//   barrier (ONE barrier/iter) and decouples mm1->mm2 within an iteration
//   (independent MFMA/load chains interleave; less lockstep sensitivity).
//   Iter 0 peeled, one tail mm2 after the loop.

#define NB 8
#define TC 4096
#define TQ 1024
#define DD 256
#define JT 32
#define NJT (TQ / JT)

typedef __attribute__((ext_vector_type(4)))  float  f32x4v;
typedef __attribute__((ext_vector_type(8)))  __bf16 bf16x8v;
typedef __attribute__((ext_vector_type(4)))  __bf16 bf16x4v;

// workspace layout (bytes)
#define QA_OFF   0                              // bf16 frag-order for mm1 A: [b][it][jm][c][L][8]  (4 MiB)
#define QX_OFF   (QA_OFF + NB*NJT*16*1024)      // bf16 frag-order for mm2 B: [b][it][mt][L][8]     (4 MiB)
#define SQ_OFF   (QX_OFF + NB*NJT*16*1024)      // f32 [NB][TQ]
#define HV_OFF   (SQ_OFF + NB*TQ*4)             // f32 [NB][DD]

__device__ __forceinline__ void async_cp16(const void* g, void* l) {
  __builtin_amdgcn_global_load_lds(
      (const __attribute__((address_space(1))) void*)g,
      (__attribute__((address_space(3))) void*)l, 16, 0, 0);
}

// ---------------- kernel 0: question preprocessing ----------------
__global__ __launch_bounds__(256) void k_qprep(const float* __restrict__ question,
                                               const float* __restrict__ w,
                                               char* __restrict__ ws) {
  uint4* qa = (uint4*)(ws + QA_OFF);
  uint4* qx = (uint4*)(ws + QX_OFF);
  float* sq = (float*)(ws + SQ_OFF);
  __shared__ __align__(16) __bf16 T[32][264];   // 528 B row stride (16-aligned)

  int bx = blockIdx.x;
  int b = bx >> 5, it = bx & 31;
  int t = threadIdx.x;
  int j = t >> 3;         // 0..31
  int seg = t & 7;        // d segment of 32

  const float* qrow = question + ((size_t)(b * TQ + it * JT + j)) * DD + seg * 32;
  const float* w2 = w + DD;

  float part = 0.f;
#pragma unroll
  for (int k = 0; k < 8; ++k) {
    float4 v  = *(const float4*)(qrow + 4 * k);
    float4 wv = *(const float4*)(w2 + seg * 32 + 4 * k);
    part += v.x * wv.x + v.y * wv.y + v.z * wv.z + v.w * wv.w;
    bf16x4v pk = {(__bf16)v.x, (__bf16)v.y, (__bf16)v.z, (__bf16)v.w};
    *(bf16x4v*)&T[j][seg * 32 + 4 * k] = pk;
  }
  part += __shfl_xor(part, 1);
  part += __shfl_xor(part, 2);
  part += __shfl_xor(part, 4);
  if (seg == 0) sq[b * TQ + it * JT + j] = part;
  __syncthreads();

  // qa chunks: ch = (jm*8+c)*64 + L ; element T[16*jm + (L&15)][32*c + 8*(L>>4) + o]
#pragma unroll
  for (int p = 0; p < 4; ++p) {
    int ch = t + 256 * p;
    int L = ch & 63, cc = ch >> 6;
    int jm = cc >> 3, c = cc & 7;
    int nh = L & 15, qh = L >> 4;
    uint4 v = *(const uint4*)&T[16 * jm + nh][32 * c + 8 * qh];
    qa[(size_t)(b * NJT + it) * 1024 + ch] = v;
  }
  // qx chunks: ch = mt*64 + L ; element T[8*(L>>4) + o][16*mt + (L&15)]
#pragma unroll
  for (int p = 0; p < 4; ++p) {
    int ch = t + 256 * p;
    int L = ch & 63, mt = ch >> 6;
    int nh = L & 15, qh = L >> 4;
    __bf16 e[8];
#pragma unroll
    for (int o = 0; o < 8; ++o) e[o] = T[8 * qh + o][16 * mt + nh];
    qx[(size_t)(b * NJT + it) * 1024 + ch] = *(const uint4*)e;
  }
}

// ---------------- kernel 1: fused scores+softmax+U+h + G chunks 0/1/2 ----------------
// 512 blocks x 256 thr (4 waves). Block owns 64 i.
// mm1 (2x2 split): wave (wi,wj) computes S^T[16j (jm=wj)][32i (it=2wi,2wi+1)]
// mm2 (d-split, DEFERRED): at iter t, wave wv computes
//   U[64i][64d_wv] += P(t-1) . qx(t-1)   (A = pa double buffer, B = regs)
__global__ __launch_bounds__(256, 2) void k_main(const float* __restrict__ context,
                                                 const float* __restrict__ w,
                                                 const char* __restrict__ ws,
                                                 float* __restrict__ hv,
                                                 float* __restrict__ out) {
  const uint4*  qa = (const uint4*)(ws + QA_OFF);
  const __bf16* qx = (const __bf16*)(ws + QX_OFF);
  const float*  sq = (const float*)(ws + SQ_OFF);

  __shared__ __align__(16) __bf16 qa_lds[2][8192];      // 2 x 16 KiB double buffer
  __shared__ __align__(16) __bf16 pa_lds[2][4][16][40]; // P double buffer (2 x 5 KiB)
  __shared__ __align__(16) float  sq_all[TQ];           // all s_q for this batch (4 KiB)
  __shared__ __align__(16) float  red_lm[2][4][16][2];  // [wj][it][nh][{l,m}]
  __shared__ __align__(16) float  rinv_lds[64];
  __shared__ __align__(16) float  bvv_lds[64];

  int bx = blockIdx.x;
  int b = bx & 7;                 // XCD-affine batch mapping
  int ig = bx >> 3;               // 0..63
  int t = threadIdx.x;
  int wv = t >> 6;
  int lane = t & 63;
  int wi = wv >> 1;               // i-half for mm1
  int wj = wv & 1;                // j-half for mm1
  int it0 = 2 * wi, it1 = 2 * wi + 1;
  int nh = lane & 15;             // col index (i for mm1 out, d for mm2 out)
  int qh = lane >> 4;             // quad

  const uint4* qa_b = qa + (size_t)b * NJT * 1024;
  const __bf16* qx_b = qx + (size_t)b * NJT * 8192;
  const float* sqb = sq + b * TQ;

  // cw3 B-frags for i-tiles it0, it1: B[k=d][n=i] = context[i][d]*w3[d]
  bf16x8v cw3f0[8], cw3f1[8];
  {
    const float* crow0 = context + ((size_t)(b * TC + ig * 64 + 32 * wi + nh)) * DD;
    const float* crow1 = crow0 + 16 * DD;
    const float* w3 = w + 2 * DD;
#pragma unroll
    for (int c = 0; c < 8; ++c) {
      int d0 = 32 * c + 8 * qh;
      float4 g0 = *(const float4*)(w3 + d0);
      float4 g1 = *(const float4*)(w3 + d0 + 4);
      float4 f0 = *(const float4*)(crow0 + d0);
      float4 f1 = *(const float4*)(crow0 + d0 + 4);
      bf16x8v fr;
      fr[0] = (__bf16)(f0.x * g0.x); fr[1] = (__bf16)(f0.y * g0.y);
      fr[2] = (__bf16)(f0.z * g0.z); fr[3] = (__bf16)(f0.w * g0.w);
      fr[4] = (__bf16)(f1.x * g1.x); fr[5] = (__bf16)(f1.y * g1.y);
      fr[6] = (__bf16)(f1.z * g1.z); fr[7] = (__bf16)(f1.w * g1.w);
      cw3f0[c] = fr;
      float4 h0 = *(const float4*)(crow1 + d0);
      float4 h1 = *(const float4*)(crow1 + d0 + 4);
      bf16x8v hr;
      hr[0] = (__bf16)(h0.x * g0.x); hr[1] = (__bf16)(h0.y * g0.y);
      hr[2] = (__bf16)(h0.z * g0.z); hr[3] = (__bf16)(h0.w * g0.w);
      hr[4] = (__bf16)(h1.x * g1.x); hr[5] = (__bf16)(h1.y * g1.y);
      hr[6] = (__bf16)(h1.z * g1.z); hr[7] = (__bf16)(h1.w * g1.w);
      cw3f1[c] = hr;
    }
  }

  // prologue: stage s_q for the whole batch (4 KiB) + qa tile 0 into buf 0
  {
    ((float4*)sq_all)[t] = ((const float4*)sqb)[t];
    const uint4* src = qa_b;  // tile 0
#pragma unroll
    for (int p = 0; p < 4; ++p) {
      int cb = wv * 64 + p * 256;                 // wave-uniform chunk base
      async_cp16(src + cb + lane, &qa_lds[0][(size_t)cb * 8]);
    }
  }

  f32x4v U[16];   // U[mi*4+nt]: rows i = mi*16+4qh+r, cols d = wv*64+nt*16+nh
#pragma unroll
  for (int k = 0; k < 16; ++k) U[k] = (f32x4v){0.f, 0.f, 0.f, 0.f};
  float m0_run = -1e30f, l0_run = 0.f;
  float m1_run = -1e30f, l1_run = 0.f;

  __syncthreads();   // drains vmcnt(0): tile 0 staged, sq_all visible

  // ---- peeled iteration 0: no deferred mm2 yet ----
  {
    // stage tile 1 into buf 1
    {
      const uint4* src = qa_b + 1024;
#pragma unroll
      for (int p = 0; p < 4; ++p) {
        int cb = wv * 64 + p * 256;
        async_cp16(src + cb + lane, &qa_lds[1][(size_t)cb * 8]);
      }
    }
    // mm1 tile 0 from buf 0
    f32x4v S0 = {0.f, 0.f, 0.f, 0.f}, S1 = {0.f, 0.f, 0.f, 0.f};
#pragma unroll
    for (int c = 0; c < 8; ++c) {
      bf16x8v ac = *(const bf16x8v*)&qa_lds[0][((wj * 8 + c) * 64 + lane) * 8];
      S0 = __builtin_amdgcn_mfma_f32_16x16x32_bf16(ac, cw3f0[c], S0, 0, 0, 0);
      S1 = __builtin_amdgcn_mfma_f32_16x16x32_bf16(ac, cw3f1[c], S1, 0, 0, 0);
    }
    float4 sqv = *(const float4*)&sq_all[16 * wj + 4 * qh];
    float a0 = S0[0] + sqv.x, a1 = S0[1] + sqv.y, a2 = S0[2] + sqv.z, a3 = S0[3] + sqv.w;
    float b0 = S1[0] + sqv.x, b1 = S1[1] + sqv.y, b2 = S1[2] + sqv.z, b3 = S1[3] + sqv.w;
    float e0 = __expf(a0), e1 = __expf(a1), e2 = __expf(a2), e3 = __expf(a3);
    float f0 = __expf(b0), f1 = __expf(b1), f2 = __expf(b2), f3 = __expf(b3);
    m0_run = fmaxf(m0_run, fmaxf(fmaxf(a0, a1), fmaxf(a2, a3)));
    m1_run = fmaxf(m1_run, fmaxf(fmaxf(b0, b1), fmaxf(b2, b3)));
    l0_run += (e0 + e1) + (e2 + e3);
    l1_run += (f0 + f1) + (f2 + f3);
    bf16x4v pk0 = {(__bf16)e0, (__bf16)e1, (__bf16)e2, (__bf16)e3};
    bf16x4v pk1 = {(__bf16)f0, (__bf16)f1, (__bf16)f2, (__bf16)f3};
    *(bf16x4v*)&pa_lds[0][it0][nh][16 * wj + 4 * qh] = pk0;
    *(bf16x4v*)&pa_lds[0][it1][nh][16 * wj + 4 * qh] = pk1;
    __syncthreads();   // tile 1 staged, P(0) visible
  }

  // ---- main loop: iter t computes P(t), consumes P(t-1) ----
  for (int itq = 1; itq < NJT; ++itq) {
    int cur = itq & 1;

    // issue B-frag loads for qx(t-1) (L2-hot); consumed by deferred mm2 below
    bf16x8v bqr[4];
    {
      const __bf16* qxt = qx_b + (size_t)(itq - 1) * 8192 + lane * 8;
#pragma unroll
      for (int nt = 0; nt < 4; ++nt)
        bqr[nt] = *(const bf16x8v*)(qxt + (size_t)(wv * 4 + nt) * 512);
    }

    // stage qa(t+1) into the spare buffer (drained by loop-end barrier)
    if (itq + 1 < NJT) {
      const uint4* src = qa_b + (size_t)(itq + 1) * 1024;
#pragma unroll
      for (int p = 0; p < 4; ++p) {
        int cb = wv * 64 + p * 256;
        async_cp16(src + cb + lane, &qa_lds[cur ^ 1][(size_t)cb * 8]);
      }
    }

    // mm1: S^T[16j (jm=wj)][32 i (it0,it1)] for tile t, from qa_lds[cur]
    f32x4v S0 = {0.f, 0.f, 0.f, 0.f}, S1 = {0.f, 0.f, 0.f, 0.f};
#pragma unroll
    for (int c = 0; c < 8; ++c) {
      bf16x8v ac = *(const bf16x8v*)&qa_lds[cur][((wj * 8 + c) * 64 + lane) * 8];
      S0 = __builtin_amdgcn_mfma_f32_16x16x32_bf16(ac, cw3f0[c], S0, 0, 0, 0);
      S1 = __builtin_amdgcn_mfma_f32_16x16x32_bf16(ac, cw3f1[c], S1, 0, 0, 0);
    }

    // deferred mm2: U += P(t-1)[64i][32j] . qx(t-1)[32j][64d_wv]
    // pa_lds[cur^1] was written at iter t-1, visible since last barrier;
    // independent of this iteration's mm1/softmax chain.
#pragma unroll
    for (int mi = 0; mi < 4; ++mi) {
      bf16x8v af = *(const bf16x8v*)&pa_lds[cur ^ 1][mi][nh][8 * qh];
#pragma unroll
      for (int nt = 0; nt < 4; ++nt)
        U[mi * 4 + nt] = __builtin_amdgcn_mfma_f32_16x16x32_bf16(af, bqr[nt], U[mi * 4 + nt], 0, 0, 0);
    }

    // softmax for tile t
    float4 sqv = *(const float4*)&sq_all[itq * JT + 16 * wj + 4 * qh];
    float a0 = S0[0] + sqv.x, a1 = S0[1] + sqv.y, a2 = S0[2] + sqv.z, a3 = S0[3] + sqv.w;
    float b0 = S1[0] + sqv.x, b1 = S1[1] + sqv.y, b2 = S1[2] + sqv.z, b3 = S1[3] + sqv.w;
    float e0 = __expf(a0), e1 = __expf(a1), e2 = __expf(a2), e3 = __expf(a3);
    float f0 = __expf(b0), f1 = __expf(b1), f2 = __expf(b2), f3 = __expf(b3);
    m0_run = fmaxf(m0_run, fmaxf(fmaxf(a0, a1), fmaxf(a2, a3)));
    m1_run = fmaxf(m1_run, fmaxf(fmaxf(b0, b1), fmaxf(b2, b3)));
    l0_run += (e0 + e1) + (e2 + e3);
    l1_run += (f0 + f1) + (f2 + f3);

    // write P(t) to pa_lds[cur]
    bf16x4v pk0 = {(__bf16)e0, (__bf16)e1, (__bf16)e2, (__bf16)e3};
    bf16x4v pk1 = {(__bf16)f0, (__bf16)f1, (__bf16)f2, (__bf16)f3};
    *(bf16x4v*)&pa_lds[cur][it0][nh][16 * wj + 4 * qh] = pk0;
    *(bf16x4v*)&pa_lds[cur][it1][nh][16 * wj + 4 * qh] = pk1;

    // single barrier: next tile staged (vmcnt drain), P(t) visible, and all
    // reads of pa_lds[cur^1]/qa_lds[cur^1] done before next overwrite.
    __syncthreads();
  }

  // ---- tail mm2 for tile NJT-1 (pa_lds[(NJT-1)&1], visible after final barrier) ----
  {
    bf16x8v bqr[4];
    const __bf16* qxt = qx_b + (size_t)(NJT - 1) * 8192 + lane * 8;
#pragma unroll
    for (int nt = 0; nt < 4; ++nt)
      bqr[nt] = *(const bf16x8v*)(qxt + (size_t)(wv * 4 + nt) * 512);
#pragma unroll
    for (int mi = 0; mi < 4; ++mi) {
      bf16x8v af = *(const bf16x8v*)&pa_lds[(NJT - 1) & 1][mi][nh][8 * qh];
#pragma unroll
      for (int nt = 0; nt < 4; ++nt)
        U[mi * 4 + nt] = __builtin_amdgcn_mfma_f32_16x16x32_bf16(af, bqr[nt], U[mi * 4 + nt], 0, 0, 0);
    }
  }

  // quad-reduce l, m over qh (lanes with same nh): partials for this wave's
  // j-half of i-tiles it0, it1.
  float lo0 = l0_run + __shfl_xor(l0_run, 16); lo0 += __shfl_xor(lo0, 32);
  float lo1 = l1_run + __shfl_xor(l1_run, 16); lo1 += __shfl_xor(lo1, 32);
  float mo0 = fmaxf(m0_run, __shfl_xor(m0_run, 16)); mo0 = fmaxf(mo0, __shfl_xor(mo0, 32));
  float mo1 = fmaxf(m1_run, __shfl_xor(m1_run, 16)); mo1 = fmaxf(mo1, __shfl_xor(mo1, 32));
  if (lane < 16) {
    red_lm[wj][it0][nh][0] = lo0; red_lm[wj][it0][nh][1] = mo0;
    red_lm[wj][it1][nh][0] = lo1; red_lm[wj][it1][nh][1] = mo1;
  }
  __syncthreads();
  if (t < 64) {
    int it = t >> 4, n = t & 15;
    float l = red_lm[0][it][n][0] + red_lm[1][it][n][0];
    float m = fmaxf(red_lm[0][it][n][1], red_lm[1][it][n][1]);
    float ri = 1.0f / l;
    rinv_lds[t] = ri;
    bvv_lds[t] = __expf(m) * ri;    // b[i] = max(A_row) = exp(m)/l
  }
  __syncthreads();

  // epilogue: wave wv owns d in [wv*64, wv*64+64) for all 64 block rows.
  // U[mi*4+nt][r]: row i = ig*64 + mi*16 + 4qh + r, col d = wv*64 + nt*16 + nh
  // Also accumulate h[d] = sum_i b[i]*context[i][d] for this block's rows.
  float hacc[4] = {0.f, 0.f, 0.f, 0.f};
#pragma unroll
  for (int mi = 0; mi < 4; ++mi) {
#pragma unroll
    for (int r = 0; r < 4; ++r) {
      int rl = mi * 16 + 4 * qh + r;
      int row = ig * 64 + rl;
      float rv = rinv_lds[rl];
      float bb = bvv_lds[rl];
      const float* crow = context + ((size_t)(b * TC + row)) * DD;
      float* orow = out + ((size_t)(b * TC + row)) * (4 * DD);
#pragma unroll
      for (int nt = 0; nt < 4; ++nt) {
        int d = wv * 64 + nt * 16 + nh;
        float c = crow[d];
        float u = U[mi * 4 + nt][r] * rv;
        orow[d] = c;
        orow[DD + d] = u;
        orow[2 * DD + d] = c * u;
        hacc[nt] += bb * c;
      }
    }
  }
  // reduce hacc over qh (4 lanes share each d), one atomic per (d) per block
#pragma unroll
  for (int nt = 0; nt < 4; ++nt) {
    float h = hacc[nt] + __shfl_xor(hacc[nt], 16);
    h += __shfl_xor(h, 32);
    if (qh == 0) atomicAdd(&hv[b * DD + wv * 64 + nt * 16 + nh], h);
  }
}

// ---------------- kernel 3: G chunk 3 = context * H ----------------
__global__ __launch_bounds__(256) void k_final(const float* __restrict__ context,
                                               const char* __restrict__ ws,
                                               float* __restrict__ out) {
  const float* hv = (const float*)(ws + HV_OFF);
  int gid = blockIdx.x * 256 + threadIdx.x;
  int row = gid >> 6;
  int d = (gid & 63) * 4;
  int b = row >> 12;
  float4 c4 = ((const float4*)context)[gid];
  float4 h4 = *(const float4*)(hv + b * DD + d);
  float4 r;
  r.x = c4.x * h4.x; r.y = c4.y * h4.y; r.z = c4.z * h4.z; r.w = c4.w * h4.w;
  *(float4*)(out + (size_t)row * TQ + 3 * DD + d) = r;
}

extern "C" void kernel_launch(void* const* d_in, const int* in_sizes, int n_in,
                              void* d_out, int out_size, void* d_ws, size_t ws_size,
                              hipStream_t stream) {
  (void)in_sizes; (void)n_in; (void)out_size; (void)ws_size;
  const float* context  = (const float*)d_in[0];
  const float* question = (const float*)d_in[1];
  const float* w        = (const float*)d_in[2];
  float* out = (float*)d_out;
  char* ws = (char*)d_ws;

  k_qprep<<<NB * NJT, 256, 0, stream>>>(question, w, ws);
  hipMemsetAsync(ws + HV_OFF, 0, NB * DD * sizeof(float), stream);
  k_main<<<NB * (TC / 64), 256, 0, stream>>>(context, w, ws,
                                             (float*)(ws + HV_OFF), out);
  k_final<<<(NB * TC * DD / 4) / 256, 256, 0, stream>>>(context, ws, out);
}

// Round 5
// 204.051 us; speedup vs baseline: 1.1409x; 1.0389x over previous
//
#include <hip/hip_runtime.h>
#include <hip/hip_bf16.h>
#include <stdint.h>
#include <stddef.h>

// BiAttentionLayer: B=8, Tc=4096, Tq=1024, D=256, fp32 in/out.
// Math: s_c (w1) cancels in softmax/U/b. exp without running max is safe
// (|S+s_q| <= ~15). b[i] = exp(m)/l.
// Round-4: d-split mm2 (wave = 64-d slice of U, P shared via LDS).
// Round-5: hybrid 2x2 mm1 split; h-reduction fused into epilogue.
// Round-6: deferred-mm2 software pipeline (P(t-1) consumed while P(t) computed).
// Round-7 (this round): registers-only mm1 A path —
//   qa workspace is already fragment-ordered, so read A-frags DIRECTLY from
//   L2 into registers and prefetch tile t+1 during iter t (in-place).
//   Deletes the qa LDS double-buffer + global_load_lds staging entirely:
//   * loop barrier is now pure lgkmcnt(0)+s_barrier (no vmcnt drain),
//   * mm1 starts immediately post-barrier with operands in registers,
//   * LDS 47->16 KiB. Critical path/iter ~= barrier -> (mm1 || pa-read->mm2)
//   -> softmax -> pa write -> barrier.

#define NB 8
#define TC 4096
#define TQ 1024
#define DD 256
#define JT 32
#define NJT (TQ / JT)

typedef __attribute__((ext_vector_type(4)))  float  f32x4v;
typedef __attribute__((ext_vector_type(8)))  __bf16 bf16x8v;
typedef __attribute__((ext_vector_type(4)))  __bf16 bf16x4v;

// workspace layout (bytes)
#define QA_OFF   0                              // bf16 frag-order for mm1 A: [b][it][jm][c][L][8]  (4 MiB)
#define QX_OFF   (QA_OFF + NB*NJT*16*1024)      // bf16 frag-order for mm2 B: [b][it][mt][L][8]     (4 MiB)
#define SQ_OFF   (QX_OFF + NB*NJT*16*1024)      // f32 [NB][TQ]
#define HV_OFF   (SQ_OFF + NB*TQ*4)             // f32 [NB][DD]

// ---------------- kernel 0: question preprocessing ----------------
__global__ __launch_bounds__(256) void k_qprep(const float* __restrict__ question,
                                               const float* __restrict__ w,
                                               char* __restrict__ ws) {
  uint4* qa = (uint4*)(ws + QA_OFF);
  uint4* qx = (uint4*)(ws + QX_OFF);
  float* sq = (float*)(ws + SQ_OFF);
  __shared__ __align__(16) __bf16 T[32][264];   // 528 B row stride (16-aligned)

  int bx = blockIdx.x;
  int b = bx >> 5, it = bx & 31;
  int t = threadIdx.x;
  int j = t >> 3;         // 0..31
  int seg = t & 7;        // d segment of 32

  const float* qrow = question + ((size_t)(b * TQ + it * JT + j)) * DD + seg * 32;
  const float* w2 = w + DD;

  float part = 0.f;
#pragma unroll
  for (int k = 0; k < 8; ++k) {
    float4 v  = *(const float4*)(qrow + 4 * k);
    float4 wv = *(const float4*)(w2 + seg * 32 + 4 * k);
    part += v.x * wv.x + v.y * wv.y + v.z * wv.z + v.w * wv.w;
    bf16x4v pk = {(__bf16)v.x, (__bf16)v.y, (__bf16)v.z, (__bf16)v.w};
    *(bf16x4v*)&T[j][seg * 32 + 4 * k] = pk;
  }
  part += __shfl_xor(part, 1);
  part += __shfl_xor(part, 2);
  part += __shfl_xor(part, 4);
  if (seg == 0) sq[b * TQ + it * JT + j] = part;
  __syncthreads();

  // qa chunks: ch = (jm*8+c)*64 + L ; element T[16*jm + (L&15)][32*c + 8*(L>>4) + o]
#pragma unroll
  for (int p = 0; p < 4; ++p) {
    int ch = t + 256 * p;
    int L = ch & 63, cc = ch >> 6;
    int jm = cc >> 3, c = cc & 7;
    int nh = L & 15, qh = L >> 4;
    uint4 v = *(const uint4*)&T[16 * jm + nh][32 * c + 8 * qh];
    qa[(size_t)(b * NJT + it) * 1024 + ch] = v;
  }
  // qx chunks: ch = mt*64 + L ; element T[8*(L>>4) + o][16*mt + (L&15)]
#pragma unroll
  for (int p = 0; p < 4; ++p) {
    int ch = t + 256 * p;
    int L = ch & 63, mt = ch >> 6;
    int nh = L & 15, qh = L >> 4;
    __bf16 e[8];
#pragma unroll
    for (int o = 0; o < 8; ++o) e[o] = T[8 * qh + o][16 * mt + nh];
    qx[(size_t)(b * NJT + it) * 1024 + ch] = *(const uint4*)e;
  }
}

// ---------------- kernel 1: fused scores+softmax+U+h + G chunks 0/1/2 ----------------
// 512 blocks x 256 thr (4 waves). Block owns 64 i.
// mm1 (2x2 split): wave (wi,wj) computes S^T[16j (jm=wj)][32i (it=2wi,2wi+1)]
//   A = registers, loaded directly from L2 (frag-ordered workspace), tile t+1
//   prefetched in-place during iter t.
// mm2 (d-split, deferred): at iter t, wave wv computes
//   U[64i][64d_wv] += P(t-1) . qx(t-1)   (A = pa LDS double buffer, B = regs)
__global__ __launch_bounds__(256, 2) void k_main(const float* __restrict__ context,
                                                 const float* __restrict__ w,
                                                 const char* __restrict__ ws,
                                                 float* __restrict__ hv,
                                                 float* __restrict__ out) {
  const uint4*  qa = (const uint4*)(ws + QA_OFF);
  const __bf16* qx = (const __bf16*)(ws + QX_OFF);
  const float*  sq = (const float*)(ws + SQ_OFF);

  __shared__ __align__(16) __bf16 pa_lds[2][4][16][40]; // P double buffer (2 x 5 KiB)
  __shared__ __align__(16) float  sq_all[TQ];           // all s_q for this batch (4 KiB)
  __shared__ __align__(16) float  red_lm[2][4][16][2];  // [wj][it][nh][{l,m}]
  __shared__ __align__(16) float  rinv_lds[64];
  __shared__ __align__(16) float  bvv_lds[64];

  int bx = blockIdx.x;
  int b = bx & 7;                 // XCD-affine batch mapping
  int ig = bx >> 3;               // 0..63
  int t = threadIdx.x;
  int wv = t >> 6;
  int lane = t & 63;
  int wi = wv >> 1;               // i-half for mm1
  int wj = wv & 1;                // j-half for mm1
  int it0 = 2 * wi, it1 = 2 * wi + 1;
  int nh = lane & 15;             // col index (i for mm1 out, d for mm2 out)
  int qh = lane >> 4;             // quad

  const uint4* qa_b = qa + (size_t)b * NJT * 1024;
  const __bf16* qx_b = qx + (size_t)b * NJT * 8192;
  const float* sqb = sq + b * TQ;

  // this wave's A-frag base: chunk index (wj*8+c)*64 + lane
  const uint4* qa_w = qa_b + (size_t)wj * 512 + lane;

  // cw3 B-frags for i-tiles it0, it1: B[k=d][n=i] = context[i][d]*w3[d]
  bf16x8v cw3f0[8], cw3f1[8];
  {
    const float* crow0 = context + ((size_t)(b * TC + ig * 64 + 32 * wi + nh)) * DD;
    const float* crow1 = crow0 + 16 * DD;
    const float* w3 = w + 2 * DD;
#pragma unroll
    for (int c = 0; c < 8; ++c) {
      int d0 = 32 * c + 8 * qh;
      float4 g0 = *(const float4*)(w3 + d0);
      float4 g1 = *(const float4*)(w3 + d0 + 4);
      float4 f0 = *(const float4*)(crow0 + d0);
      float4 f1 = *(const float4*)(crow0 + d0 + 4);
      bf16x8v fr;
      fr[0] = (__bf16)(f0.x * g0.x); fr[1] = (__bf16)(f0.y * g0.y);
      fr[2] = (__bf16)(f0.z * g0.z); fr[3] = (__bf16)(f0.w * g0.w);
      fr[4] = (__bf16)(f1.x * g1.x); fr[5] = (__bf16)(f1.y * g1.y);
      fr[6] = (__bf16)(f1.z * g1.z); fr[7] = (__bf16)(f1.w * g1.w);
      cw3f0[c] = fr;
      float4 h0 = *(const float4*)(crow1 + d0);
      float4 h1 = *(const float4*)(crow1 + d0 + 4);
      bf16x8v hr;
      hr[0] = (__bf16)(h0.x * g0.x); hr[1] = (__bf16)(h0.y * g0.y);
      hr[2] = (__bf16)(h0.z * g0.z); hr[3] = (__bf16)(h0.w * g0.w);
      hr[4] = (__bf16)(h1.x * g1.x); hr[5] = (__bf16)(h1.y * g1.y);
      hr[6] = (__bf16)(h1.z * g1.z); hr[7] = (__bf16)(h1.w * g1.w);
      cw3f1[c] = hr;
    }
  }

  // prologue: stage s_q (4 KiB) to LDS; load A-frags for tile 0 into regs
  ((float4*)sq_all)[t] = ((const float4*)sqb)[t];

  bf16x8v afr[8];
#pragma unroll
  for (int c = 0; c < 8; ++c) afr[c] = *(const bf16x8v*)(qa_w + c * 64);

  f32x4v U[16];   // U[mi*4+nt]: rows i = mi*16+4qh+r, cols d = wv*64+nt*16+nh
#pragma unroll
  for (int k = 0; k < 16; ++k) U[k] = (f32x4v){0.f, 0.f, 0.f, 0.f};
  float m0_run = -1e30f, l0_run = 0.f;
  float m1_run = -1e30f, l1_run = 0.f;

  __syncthreads();   // sq_all visible

  // ---- peeled iteration 0: mm1 + softmax + P write (no deferred mm2 yet) ----
  {
    f32x4v S0 = {0.f, 0.f, 0.f, 0.f}, S1 = {0.f, 0.f, 0.f, 0.f};
#pragma unroll
    for (int c = 0; c < 8; ++c) {
      S0 = __builtin_amdgcn_mfma_f32_16x16x32_bf16(afr[c], cw3f0[c], S0, 0, 0, 0);
      S1 = __builtin_amdgcn_mfma_f32_16x16x32_bf16(afr[c], cw3f1[c], S1, 0, 0, 0);
    }
    // prefetch tile 1 A-frags (in-place; afr dead after mm1)
#pragma unroll
    for (int c = 0; c < 8; ++c) afr[c] = *(const bf16x8v*)(qa_w + 1024 + c * 64);

    float4 sqv = *(const float4*)&sq_all[16 * wj + 4 * qh];
    float a0 = S0[0] + sqv.x, a1 = S0[1] + sqv.y, a2 = S0[2] + sqv.z, a3 = S0[3] + sqv.w;
    float b0 = S1[0] + sqv.x, b1 = S1[1] + sqv.y, b2 = S1[2] + sqv.z, b3 = S1[3] + sqv.w;
    float e0 = __expf(a0), e1 = __expf(a1), e2 = __expf(a2), e3 = __expf(a3);
    float f0 = __expf(b0), f1 = __expf(b1), f2 = __expf(b2), f3 = __expf(b3);
    m0_run = fmaxf(m0_run, fmaxf(fmaxf(a0, a1), fmaxf(a2, a3)));
    m1_run = fmaxf(m1_run, fmaxf(fmaxf(b0, b1), fmaxf(b2, b3)));
    l0_run += (e0 + e1) + (e2 + e3);
    l1_run += (f0 + f1) + (f2 + f3);
    bf16x4v pk0 = {(__bf16)e0, (__bf16)e1, (__bf16)e2, (__bf16)e3};
    bf16x4v pk1 = {(__bf16)f0, (__bf16)f1, (__bf16)f2, (__bf16)f3};
    *(bf16x4v*)&pa_lds[0][it0][nh][16 * wj + 4 * qh] = pk0;
    *(bf16x4v*)&pa_lds[0][it1][nh][16 * wj + 4 * qh] = pk1;
    asm volatile("s_waitcnt lgkmcnt(0)\n\ts_barrier" ::: "memory");
  }

  // ---- main loop: iter t computes P(t), consumes P(t-1); no vmcnt at barrier ----
  for (int itq = 1; itq < NJT; ++itq) {
    int cur = itq & 1;

    // issue B-frag loads for qx(t-1); latency hides under mm1 + pa ds_reads
    bf16x8v bqr[4];
    {
      const __bf16* qxt = qx_b + (size_t)(itq - 1) * 8192 + lane * 8;
#pragma unroll
      for (int nt = 0; nt < 4; ++nt)
        bqr[nt] = *(const bf16x8v*)(qxt + (size_t)(wv * 4 + nt) * 512);
    }

    // mm1: operands already in registers -> starts immediately post-barrier
    f32x4v S0 = {0.f, 0.f, 0.f, 0.f}, S1 = {0.f, 0.f, 0.f, 0.f};
#pragma unroll
    for (int c = 0; c < 8; ++c) {
      S0 = __builtin_amdgcn_mfma_f32_16x16x32_bf16(afr[c], cw3f0[c], S0, 0, 0, 0);
      S1 = __builtin_amdgcn_mfma_f32_16x16x32_bf16(afr[c], cw3f1[c], S1, 0, 0, 0);
    }

    // prefetch tile t+1 A-frags in-place (afr dead after mm1); lands during
    // softmax/barrier of this iter
    if (itq + 1 < NJT) {
#pragma unroll
      for (int c = 0; c < 8; ++c)
        afr[c] = *(const bf16x8v*)(qa_w + (size_t)(itq + 1) * 1024 + c * 64);
    }

    // deferred mm2: U += P(t-1)[64i][32j] . qx(t-1)[32j][64d_wv]
#pragma unroll
    for (int mi = 0; mi < 4; ++mi) {
      bf16x8v af = *(const bf16x8v*)&pa_lds[cur ^ 1][mi][nh][8 * qh];
#pragma unroll
      for (int nt = 0; nt < 4; ++nt)
        U[mi * 4 + nt] = __builtin_amdgcn_mfma_f32_16x16x32_bf16(af, bqr[nt], U[mi * 4 + nt], 0, 0, 0);
    }

    // softmax for tile t
    float4 sqv = *(const float4*)&sq_all[itq * JT + 16 * wj + 4 * qh];
    float a0 = S0[0] + sqv.x, a1 = S0[1] + sqv.y, a2 = S0[2] + sqv.z, a3 = S0[3] + sqv.w;
    float b0 = S1[0] + sqv.x, b1 = S1[1] + sqv.y, b2 = S1[2] + sqv.z, b3 = S1[3] + sqv.w;
    float e0 = __expf(a0), e1 = __expf(a1), e2 = __expf(a2), e3 = __expf(a3);
    float f0 = __expf(b0), f1 = __expf(b1), f2 = __expf(b2), f3 = __expf(b3);
    m0_run = fmaxf(m0_run, fmaxf(fmaxf(a0, a1), fmaxf(a2, a3)));
    m1_run = fmaxf(m1_run, fmaxf(fmaxf(b0, b1), fmaxf(b2, b3)));
    l0_run += (e0 + e1) + (e2 + e3);
    l1_run += (f0 + f1) + (f2 + f3);

    // write P(t) to pa_lds[cur]
    bf16x4v pk0 = {(__bf16)e0, (__bf16)e1, (__bf16)e2, (__bf16)e3};
    bf16x4v pk1 = {(__bf16)f0, (__bf16)f1, (__bf16)f2, (__bf16)f3};
    *(bf16x4v*)&pa_lds[cur][it0][nh][16 * wj + 4 * qh] = pk0;
    *(bf16x4v*)&pa_lds[cur][it1][nh][16 * wj + 4 * qh] = pk1;

    // lgkm-only barrier: P(t) visible; all pa[cur^1] reads done before next
    // overwrite. No vmem to drain (A-frags/bqr are register loads).
    asm volatile("s_waitcnt lgkmcnt(0)\n\ts_barrier" ::: "memory");
  }

  // ---- tail mm2 for tile NJT-1 ----
  {
    bf16x8v bqr[4];
    const __bf16* qxt = qx_b + (size_t)(NJT - 1) * 8192 + lane * 8;
#pragma unroll
    for (int nt = 0; nt < 4; ++nt)
      bqr[nt] = *(const bf16x8v*)(qxt + (size_t)(wv * 4 + nt) * 512);
#pragma unroll
    for (int mi = 0; mi < 4; ++mi) {
      bf16x8v af = *(const bf16x8v*)&pa_lds[(NJT - 1) & 1][mi][nh][8 * qh];
#pragma unroll
      for (int nt = 0; nt < 4; ++nt)
        U[mi * 4 + nt] = __builtin_amdgcn_mfma_f32_16x16x32_bf16(af, bqr[nt], U[mi * 4 + nt], 0, 0, 0);
    }
  }

  // quad-reduce l, m over qh (lanes with same nh): partials for this wave's
  // j-half of i-tiles it0, it1.
  float lo0 = l0_run + __shfl_xor(l0_run, 16); lo0 += __shfl_xor(lo0, 32);
  float lo1 = l1_run + __shfl_xor(l1_run, 16); lo1 += __shfl_xor(lo1, 32);
  float mo0 = fmaxf(m0_run, __shfl_xor(m0_run, 16)); mo0 = fmaxf(mo0, __shfl_xor(mo0, 32));
  float mo1 = fmaxf(m1_run, __shfl_xor(m1_run, 16)); mo1 = fmaxf(mo1, __shfl_xor(mo1, 32));
  if (lane < 16) {
    red_lm[wj][it0][nh][0] = lo0; red_lm[wj][it0][nh][1] = mo0;
    red_lm[wj][it1][nh][0] = lo1; red_lm[wj][it1][nh][1] = mo1;
  }
  __syncthreads();
  if (t < 64) {
    int it = t >> 4, n = t & 15;
    float l = red_lm[0][it][n][0] + red_lm[1][it][n][0];
    float m = fmaxf(red_lm[0][it][n][1], red_lm[1][it][n][1]);
    float ri = 1.0f / l;
    rinv_lds[t] = ri;
    bvv_lds[t] = __expf(m) * ri;    // b[i] = max(A_row) = exp(m)/l
  }
  __syncthreads();

  // epilogue: wave wv owns d in [wv*64, wv*64+64) for all 64 block rows.
  // U[mi*4+nt][r]: row i = ig*64 + mi*16 + 4qh + r, col d = wv*64 + nt*16 + nh
  // Also accumulate h[d] = sum_i b[i]*context[i][d] for this block's rows.
  float hacc[4] = {0.f, 0.f, 0.f, 0.f};
#pragma unroll
  for (int mi = 0; mi < 4; ++mi) {
#pragma unroll
    for (int r = 0; r < 4; ++r) {
      int rl = mi * 16 + 4 * qh + r;
      int row = ig * 64 + rl;
      float rv = rinv_lds[rl];
      float bb = bvv_lds[rl];
      const float* crow = context + ((size_t)(b * TC + row)) * DD;
      float* orow = out + ((size_t)(b * TC + row)) * (4 * DD);
#pragma unroll
      for (int nt = 0; nt < 4; ++nt) {
        int d = wv * 64 + nt * 16 + nh;
        float c = crow[d];
        float u = U[mi * 4 + nt][r] * rv;
        orow[d] = c;
        orow[DD + d] = u;
        orow[2 * DD + d] = c * u;
        hacc[nt] += bb * c;
      }
    }
  }
  // reduce hacc over qh (4 lanes share each d), one atomic per (d) per block
#pragma unroll
  for (int nt = 0; nt < 4; ++nt) {
    float h = hacc[nt] + __shfl_xor(hacc[nt], 16);
    h += __shfl_xor(h, 32);
    if (qh == 0) atomicAdd(&hv[b * DD + wv * 64 + nt * 16 + nh], h);
  }
}

// ---------------- kernel 3: G chunk 3 = context * H ----------------
__global__ __launch_bounds__(256) void k_final(const float* __restrict__ context,
                                               const char* __restrict__ ws,
                                               float* __restrict__ out) {
  const float* hv = (const float*)(ws + HV_OFF);
  int gid = blockIdx.x * 256 + threadIdx.x;
  int row = gid >> 6;
  int d = (gid & 63) * 4;
  int b = row >> 12;
  float4 c4 = ((const float4*)context)[gid];
  float4 h4 = *(const float4*)(hv + b * DD + d);
  float4 r;
  r.x = c4.x * h4.x; r.y = c4.y * h4.y; r.z = c4.z * h4.z; r.w = c4.w * h4.w;
  *(float4*)(out + (size_t)row * TQ + 3 * DD + d) = r;
}

extern "C" void kernel_launch(void* const* d_in, const int* in_sizes, int n_in,
                              void* d_out, int out_size, void* d_ws, size_t ws_size,
                              hipStream_t stream) {
  (void)in_sizes; (void)n_in; (void)out_size; (void)ws_size;
  const float* context  = (const float*)d_in[0];
  const float* question = (const float*)d_in[1];
  const float* w        = (const float*)d_in[2];
  float* out = (float*)d_out;
  char* ws = (char*)d_ws;

  k_qprep<<<NB * NJT, 256, 0, stream>>>(question, w, ws);
  hipMemsetAsync(ws + HV_OFF, 0, NB * DD * sizeof(float), stream);
  k_main<<<NB * (TC / 64), 256, 0, stream>>>(context, w, ws,
                                             (float*)(ws + HV_OFF), out);
  k_final<<<(NB * TC * DD / 4) / 256, 256, 0, stream>>>(context, ws, out);
}